// Round 9
// baseline (2635.760 us; speedup 1.0000x reference)
//
#include <hip/hip_runtime.h>

#define NBUS 118
#define BATCH 4096
#define NN (BATCH * NBUS)          // 483328 nodes
#define END_E (4 * NN)             // 1933312 no-diag edges
#define EF_E (END_E + NN)          // 2416640 full edges
#define NLAYERS 10

#define SSPAN 2048                 // src bucket span (pow2: shift/mask keys)
#define NSB 236                    // src buckets: 236*2048 == NN exactly
#define DSPAN 472                  // dst combine span = 4*NBUS (batch-aligned)
#define NDB 1024                   // 1024*472 == NN exactly
#define TILE 4096                  // edges per binA block
#define ND_TILES (END_E / TILE)    // 472 (exact)
#define F_TILES  (EF_E / TILE)     // 590 (exact)
#define CAP_ND 8960                // per-src-bucket cap: mean 8192, +8.5 sigma
#define CAP_F  11008               // per-src-bucket cap: mean 10240, +7.6 sigma
#define SPLIT 4                    // scatter blocks per src bucket -> 944 blocks

#define NERR 64                    // spread error-atomic slots (stride 16 floats = 64B)

__device__ __forceinline__ float wf(unsigned bits) { return __int_as_float((int)bits); }

// ---------- K1: p, denomInv, cursors, err partials, aggr zero ----------
__global__ void init_kernel(const float* __restrict__ x,
                            const float* __restrict__ ybus,
                            float* __restrict__ p,
                            float* __restrict__ denomInv,
                            int* __restrict__ cursor_nd,
                            int* __restrict__ cursor_f,
                            float* __restrict__ errPartial,
                            float* __restrict__ aggrF,
                            float* __restrict__ aggrN) {
    int tid = blockIdx.x * blockDim.x + threadIdx.x;
    int stride = gridDim.x * blockDim.x;
    for (int i = tid; i < NN; i += stride) {
        float2 xi = ((const float2*)x)[i];
        p[i] = xi.x - xi.y;
        int b = i / NBUS;
        int j = i - b * NBUS;
        denomInv[i] = 1.0f / (ybus[b * (NBUS * NBUS) + j * (NBUS + 1)] * 100.0f);
        aggrF[i] = 0.0f;
        aggrN[i] = 0.0f;
    }
    for (int i = tid; i < (NLAYERS + 1) * NERR * 16; i += stride) errPartial[i] = 0.0f;
    if (tid < NSB) {
        cursor_nd[tid] = tid * CAP_ND;
        cursor_f[tid]  = tid * CAP_F;
    }
}

// ---------- K2 (binA): tile -> LDS bin by SRC bucket (span 2048) -> staging ----------
// staged entry: .x = dst(19b) | srcLocal(11b)<<19 ; .y = bits(w*100)
__global__ __launch_bounds__(256) void binA_kernel(
        const int* __restrict__ src_nd, const int* __restrict__ dst_nd,
        const float* __restrict__ ea_nd,
        const int* __restrict__ src_f, const int* __restrict__ dst_f,
        const float* __restrict__ ea_f,
        int* __restrict__ cursor_nd, int* __restrict__ cursor_f,
        uint2* __restrict__ stg_nd, uint2* __restrict__ stg_f) {
    __shared__ uint2 buf[TILE];            // 32 KB
    __shared__ unsigned char sb[TILE];     // 4 KB
    __shared__ int hist[256];
    __shared__ int scanA[256];
    __shared__ int segStart[256];
    __shared__ int segGBase[256];

    bool isF = blockIdx.x >= ND_TILES;
    int tile = isF ? (blockIdx.x - ND_TILES) : blockIdx.x;
    const int* src = isF ? src_f : src_nd;
    const int* dst = isF ? dst_f : dst_nd;
    const float* ea = isF ? ea_f : ea_nd;
    int* cursor = isF ? cursor_f : cursor_nd;
    uint2* stg = isF ? stg_f : stg_nd;
    int cap = isF ? CAP_F : CAP_ND;

    int tid = threadIdx.x;
    int base = tile * TILE;

    hist[tid] = 0;
    __syncthreads();

    #pragma unroll
    for (int k = 0; k < TILE / 256; ++k) {
        unsigned s = (unsigned)src[base + k * 256 + tid];
        atomicAdd(&hist[s >> 11], 1);          // src bucket (0..235)
    }
    __syncthreads();

    int cnt = hist[tid];
    scanA[tid] = cnt;
    __syncthreads();
    for (int off = 1; off < 256; off <<= 1) {
        int t = (tid >= off) ? scanA[tid - off] : 0;
        __syncthreads();
        scanA[tid] += t;
        __syncthreads();
    }
    int excl = scanA[tid] - cnt;
    segStart[tid] = excl;
    hist[tid] = excl;
    if (tid < NSB && cnt > 0) segGBase[tid] = atomicAdd(&cursor[tid], cnt);
    __syncthreads();

    #pragma unroll
    for (int k = 0; k < TILE / 256; ++k) {
        int e = base + k * 256 + tid;
        unsigned s = (unsigned)src[e];
        unsigned bkt = s >> 11;
        int pos = atomicAdd(&hist[bkt], 1);
        unsigned srcl = s & 2047u;
        buf[pos] = make_uint2((unsigned)dst[e] | (srcl << 19),
                              (unsigned)__float_as_int(ea[e] * 100.0f));
        sb[pos] = (unsigned char)bkt;
    }
    __syncthreads();

    #pragma unroll
    for (int k = 0; k < TILE / 256; ++k) {
        int slot = k * 256 + tid;
        int bkt = sb[slot];
        int gpos = segGBase[bkt] + (slot - segStart[bkt]);
        if (gpos < (bkt + 1) * cap)  // freak-overflow guard
            stg[gpos] = buf[slot];
    }
}

// ---------- K3: layer 0 (theta = 0): out0 = p*denomInv - slack ----------
__global__ void out0_kernel(const float* __restrict__ p,
                            const float* __restrict__ denomInv,
                            float* __restrict__ out) {
    int b = blockIdx.x;
    int j = threadIdx.x;
    int i = b * NBUS + j;
    __shared__ float z0;
    float z = 0.0f;
    if (j < NBUS) z = p[i] * denomInv[i];
    if (j == 0) z0 = z;
    __syncthreads();
    if (j < NBUS) out[i] = z - z0;
}

// ---------- K4 (scatter): push model. Block = (src bucket, part). ----------
// Loads its 8KB cur tile into LDS (coalesced), streams its edge slice
// (coalesced), and scatters msg = tile[srcl]*w via fire-and-forget global
// atomicAdd into aggrF / aggrN. No dependent gather waits anywhere.
template <bool DO_ND>
__global__ __launch_bounds__(512) void scatter_kernel(
        const uint2* __restrict__ stg_nd, const uint2* __restrict__ stg_f,
        const int* __restrict__ cursor_nd, const int* __restrict__ cursor_f,
        const float* __restrict__ cur,
        float* __restrict__ aggrF, float* __restrict__ aggrN) {
    __shared__ float tile[SSPAN];   // 8 KB
    int tid = threadIdx.x;
    int sb = blockIdx.x / SPLIT;
    int part = blockIdx.x - sb * SPLIT;

    // coalesced tile load: 512 threads x float4 = 2048 floats
    ((float4*)tile)[tid] = ((const float4*)(cur + (long)sb * SSPAN))[tid];
    __syncthreads();

    {   // F side
        int tot = cursor_f[sb] - sb * CAP_F; if (tot > CAP_F) tot = CAP_F;
        int beg = (int)(((long)tot * part) / SPLIT);
        int end = (int)(((long)tot * (part + 1)) / SPLIT);
        const uint2* sg = stg_f + (long)sb * CAP_F;
        for (int i = beg + tid; i < end; i += 512) {
            uint2 e = sg[i];
            atomicAdd(&aggrF[e.x & 0x7FFFFu], tile[e.x >> 19] * wf(e.y));
        }
    }
    if (DO_ND) {   // ND side
        int tot = cursor_nd[sb] - sb * CAP_ND; if (tot > CAP_ND) tot = CAP_ND;
        int beg = (int)(((long)tot * part) / SPLIT);
        int end = (int)(((long)tot * (part + 1)) / SPLIT);
        const uint2* sg = stg_nd + (long)sb * CAP_ND;
        for (int i = beg + tid; i < end; i += 512) {
            uint2 e = sg[i];
            atomicAdd(&aggrN[e.x & 0x7FFFFu], tile[e.x >> 19] * wf(e.y));
        }
    }
}

// ---------- K5 (combine): coalesced aggr read -> err + z + fused slack; reset aggr ----------
template <bool DO_OUT>
__global__ __launch_bounds__(512) void combine_kernel(
        float* __restrict__ aggrF, float* __restrict__ aggrN,
        const float* __restrict__ p, const float* __restrict__ denomInv,
        float* __restrict__ out,
        float* __restrict__ errPart /* NERR slots, stride 16 */) {
    __shared__ float zbuf[DSPAN];
    __shared__ float ws[8];
    int tid = threadIdx.x;
    int fb = blockIdx.x;
    int gbase = fb * DSPAN;

    float acc = 0.0f;
    if (tid < DSPAN) {
        int i = gbase + tid;
        float pv = p[i];
        float af = aggrF[i];
        acc = fabsf(pv - af);
        if (DO_OUT) {
            aggrF[i] = 0.0f;                       // reset for next layer
            float an = aggrN[i];
            aggrN[i] = 0.0f;
            zbuf[tid] = (pv - an) * denomInv[i];
        }
    }
    if (DO_OUT) {
        __syncthreads();
        if (tid < DSPAN)
            out[gbase + tid] = zbuf[tid] - zbuf[(tid / NBUS) * NBUS];
    }
    for (int off = 32; off > 0; off >>= 1) acc += __shfl_down(acc, off, 64);
    if ((tid & 63) == 0) ws[tid >> 6] = acc;
    __syncthreads();
    if (tid == 0) {
        float t = 0.0f;
        #pragma unroll
        for (int w = 0; w < 8; ++w) t += ws[w];
        atomicAdd(&errPart[(fb & (NERR - 1)) * 16], t);
    }
}

// ---------- K6: reduce err partials -> errs[11] ----------
__global__ void err_reduce_kernel(const float* __restrict__ errPartial,
                                  float* __restrict__ errs) {
    int l = blockIdx.x;
    int t = threadIdx.x;  // 64
    float v = errPartial[l * (NERR * 16) + t * 16];
    for (int off = 32; off > 0; off >>= 1) v += __shfl_down(v, off, 64);
    if (t == 0) errs[l] = v;
}

extern "C" void kernel_launch(void* const* d_in, const int* in_sizes, int n_in,
                              void* d_out, int out_size, void* d_ws, size_t ws_size,
                              hipStream_t stream) {
    const float* x     = (const float*)d_in[0];
    const int*   ei_nd = (const int*)d_in[2];
    const float* ea_nd = (const float*)d_in[3];
    const int*   ei    = (const int*)d_in[4];
    const float* ea    = (const float*)d_in[5];
    const float* ybus  = (const float*)d_in[6];

    float* out_f = (float*)d_out;
    float* errs  = out_f + NN;

    // workspace carve (4-byte units)
    float* wsf        = (float*)d_ws;
    float* p          = wsf;          wsf += NN;
    float* denomInv   = wsf;          wsf += NN;
    float* outA       = wsf;          wsf += NN;
    float* outB       = wsf;          wsf += NN;
    float* aggrF      = wsf;          wsf += NN;
    float* aggrN      = wsf;          wsf += NN;
    int*   cursor_nd  = (int*)wsf;    wsf += 256;
    int*   cursor_f   = (int*)wsf;    wsf += 256;
    float* errPartial = wsf;          wsf += (NLAYERS + 1) * NERR * 16;  // 11264
    uint2* stg_nd     = (uint2*)wsf;  wsf += 2LL * NSB * CAP_ND;
    uint2* stg_f      = (uint2*)wsf;  wsf += 2LL * NSB * CAP_F;

    const int* src_nd = ei_nd;
    const int* dst_nd = ei_nd + END_E;
    const int* src_f  = ei;
    const int* dst_f  = ei + EF_E;

    // ---- build phase ----
    init_kernel<<<2048, 256, 0, stream>>>(x, ybus, p, denomInv,
                                          cursor_nd, cursor_f, errPartial,
                                          aggrF, aggrN);
    binA_kernel<<<ND_TILES + F_TILES, 256, 0, stream>>>(
        src_nd, dst_nd, ea_nd, src_f, dst_f, ea,
        cursor_nd, cursor_f, stg_nd, stg_f);

    // ---- iterate phase: per layer = scatter (push, atomics) + combine ----
    out0_kernel<<<BATCH, 128, 0, stream>>>(p, denomInv, outA);
    const float* cur = outA;
    for (int k = 1; k <= NLAYERS; ++k) {
        float* nxt = (k == NLAYERS) ? out_f : ((k & 1) ? outB : outA);
        scatter_kernel<true><<<NSB * SPLIT, 512, 0, stream>>>(
            stg_nd, stg_f, cursor_nd, cursor_f, cur, aggrF, aggrN);
        combine_kernel<true><<<NDB, 512, 0, stream>>>(
            aggrF, aggrN, p, denomInv, nxt,
            errPartial + (long)(k - 1) * NERR * 16);
        cur = nxt;
    }
    scatter_kernel<false><<<NSB * SPLIT, 512, 0, stream>>>(
        stg_nd, stg_f, cursor_nd, cursor_f, cur, aggrF, aggrN);
    combine_kernel<false><<<NDB, 512, 0, stream>>>(
        aggrF, aggrN, p, denomInv, nullptr,
        errPartial + (long)NLAYERS * NERR * 16);
    err_reduce_kernel<<<NLAYERS + 1, 64, 0, stream>>>(errPartial, errs);
}